// Round 1
// baseline (274.001 us; speedup 1.0000x reference)
//
#include <hip/hip_runtime.h>

#define S_LEN 2048
#define DIM   2048
#define NH    16
#define NKV   4
#define HD    128
#define WIN   512
#define BATCH 2

typedef __bf16 bf16x8 __attribute__((ext_vector_type(8)));
typedef __bf16 bf16x4 __attribute__((ext_vector_type(4)));
typedef float  f32x4  __attribute__((ext_vector_type(4)));

union U8 { bf16x8 v; bf16x4 h[2]; };

__device__ inline void async_load16(const void* g, void* l) {
  __builtin_amdgcn_global_load_lds(
      (const __attribute__((address_space(1))) unsigned int*)g,
      (__attribute__((address_space(3))) unsigned int*)l, 16, 0, 0);
}

// ------------- merged preprocess: x cast | weight cast+perm | rope tables ----
__global__ __launch_bounds__(256) void preprocess_kernel(
    const float* __restrict__ x,
    const float* __restrict__ Wq, const float* __restrict__ Wk,
    const float* __restrict__ Wv, const float* __restrict__ Wo,
    __bf16* __restrict__ xb, __bf16* __restrict__ wqkv, __bf16* __restrict__ wob,
    float* __restrict__ cosT, float* __restrict__ sinT) {
  const int blk = blockIdx.x, tid = threadIdx.x;
  if (blk < 8192) {
    int i = blk * 256 + tid;  // x: 2097152 float4
    float4 v = ((const float4*)x)[i];
    bf16x4 o;
    o[0] = (__bf16)v.x; o[1] = (__bf16)v.y; o[2] = (__bf16)v.z; o[3] = (__bf16)v.w;
    ((bf16x4*)xb)[i] = o;
  } else if (blk < 18432) {
    int i = (blk - 8192) * 256 + tid;  // weights: 5120 rows x 512 float4
    int orow = i >> 9, c = i & 511;
    const float* src;
    __bf16* dst;
    long soff;
    if (orow < 2048) {
      int n = orow & 127;
      int sr = (orow & ~127) + ((n >> 5) << 4) + (n & 15) + (((n >> 4) & 1) << 6);
      src = Wq; soff = (long)sr * 512 + c; dst = wqkv + (long)orow * 2048;
    } else if (orow < 2560) {
      int lr = orow - 2048, n = lr & 127;
      int sr = (lr & ~127) + ((n >> 5) << 4) + (n & 15) + (((n >> 4) & 1) << 6);
      src = Wk; soff = (long)sr * 512 + c; dst = wqkv + (long)orow * 2048;
    } else if (orow < 3072) {
      src = Wv; soff = (long)(orow - 2560) * 512 + c; dst = wqkv + (long)orow * 2048;
    } else {
      src = Wo; soff = (long)(orow - 3072) * 512 + c; dst = wob + (long)(orow - 3072) * 2048;
    }
    float4 v = ((const float4*)src)[soff];
    bf16x4 o;
    o[0] = (__bf16)v.x; o[1] = (__bf16)v.y; o[2] = (__bf16)v.z; o[3] = (__bf16)v.w;
    ((bf16x4*)dst)[c] = o;
  } else {
    int idx = (blk - 18432) * 256 + tid;  // rope: 131072
    int s = idx >> 6, d = idx & 63;
    float f = (float)s * powf(10000.f, -(float)d * (1.f / 64.f));
    float sn, cs;
    sincosf(f, &sn, &cs);
    cosT[idx] = cs;
    sinT[idx] = sn;
  }
}

// -------- O-projection GEMM: m97 structure (2-barrier, 1 buf) -----
__global__ __launch_bounds__(256) void gemm_bt(
    const __bf16* __restrict__ A, const __bf16* __restrict__ Bt,
    float* __restrict__ C, int M, int N, int K) {
  __shared__ __bf16 As[128 * 32];
  __shared__ __bf16 Bs[128 * 32];
  const int t = threadIdx.x;
  const int wid = t >> 6, lane = t & 63;
  const int quad = lane >> 4, l15 = lane & 15;
  const long m0 = (long)blockIdx.x * 128, n0 = (long)blockIdx.y * 128;
  const int wm = (wid >> 1) * 64, wn = (wid & 1) * 64;

  const __bf16* ga = A + (m0 + (t >> 2)) * (long)K + (t & 3) * 8;
  const __bf16* gb = Bt + (n0 + (t >> 2)) * (long)K + (t & 3) * 8;
  char* lA = (char*)As + wid * 1024;
  char* lB = (char*)Bs + wid * 1024;
  const long rstride = 64L * K;

  f32x4 zero = {0.f, 0.f, 0.f, 0.f};
  f32x4 acc[4][4];
#pragma unroll
  for (int i = 0; i < 4; ++i)
#pragma unroll
    for (int j = 0; j < 4; ++j) acc[i][j] = zero;

  for (int k0 = 0; k0 < K; k0 += 32) {
    async_load16(ga + k0, lA);
    async_load16(ga + k0 + rstride, lA + 4096);
    async_load16(gb + k0, lB);
    async_load16(gb + k0 + rstride, lB + 4096);
    __syncthreads();
    bf16x8 af[4], bfr[4];
#pragma unroll
    for (int i = 0; i < 4; ++i) {
      af[i] = *(const bf16x8*)(As + (wm + i * 16 + l15) * 32 + quad * 8);
      bfr[i] = *(const bf16x8*)(Bs + (wn + i * 16 + l15) * 32 + quad * 8);
    }
#pragma unroll
    for (int i = 0; i < 4; ++i)
#pragma unroll
      for (int j = 0; j < 4; ++j)
        acc[i][j] = __builtin_amdgcn_mfma_f32_16x16x32_bf16(af[i], bfr[j], acc[i][j], 0, 0, 0);
    __syncthreads();
  }

#pragma unroll
  for (int i = 0; i < 4; ++i)
#pragma unroll
    for (int j = 0; j < 4; ++j)
#pragma unroll
      for (int r = 0; r < 4; ++r)
        C[(m0 + wm + i * 16 + quad * 4 + r) * (long)N + n0 + wn + j * 16 + l15] = acc[i][j][r];
}

// -------- QKV GEMM: 256x256 tile, BK=64, 8 waves (2Mx4N), 8-phase schedule ---
// T2 XOR-swizzle on ds_read (staged via inverse-swizzled global src, rule #21),
// T3/T4 counted vmcnt(8) (2-tile prefetch, never drained to 0 in main loop),
// T5 setprio around each 16-MFMA cluster. Fused RMSNorm/RoPE/gain/V-transpose.
__global__ __launch_bounds__(512, 2) void gemm_qkv(
    const __bf16* __restrict__ A, const __bf16* __restrict__ Bt,
    const float* __restrict__ gain,
    const float* __restrict__ cosT, const float* __restrict__ sinT,
    __bf16* __restrict__ Qo, __bf16* __restrict__ Ko, __bf16* __restrict__ Vt) {
  extern __shared__ char smem[];  // 128 KiB: [buf][As0|As1|Bs0|Bs1], 16 KiB each
  constexpr int K = 2048;
  constexpr int NT = 32;  // K / 64
  const int t = threadIdx.x;
  const int wid = t >> 6, lane = t & 63;
  const int quad = lane >> 4, l15 = lane & 15;
  const int wr = wid >> 2, wc = wid & 3;     // 2Mx4N wave grid
  const long m0 = (long)blockIdx.x * 256;
  const long n0 = (long)blockIdx.y * 256;

  // ---- staging addressing: linear LDS dest, inverse-swizzled global source.
  // LDS linear slot p = j*8192 + wid*1024 + lane*16 -> row = p>>7,
  // phys 16B chunk = lane&7; it must hold logical chunk (lane&7)^((row&7)&7).
  const int srw = (wid << 3) + (lane >> 3);           // 0..63 within a 64-row block
  const int c8 = (lane & 7) ^ ((lane >> 3) & 7);      // permuted 16B chunk
  const __bf16* ag = A + (m0 + srw) * (long)K + c8 * 8;
  const __bf16* bg = Bt + (n0 + srw) * (long)K + c8 * 8;
  char* const lbase = smem + (wid << 10);

  auto stage = [&](int buf, int op, int h, int j, int kt) {
    const __bf16* g = (op ? bg : ag) + (long)((h << 7) + (j << 6)) * K + (long)kt * 64;
    async_load16(g, lbase + buf * 65536 + op * 32768 + h * 16384 + j * 8192);
  };

  // ---- fragment read addressing (swizzled): colbyte ^= (row&7)<<4, row&7==l15&7
  const int swz = (l15 & 7) << 4;
  const int col0 = (quad * 16) ^ swz;        // kk=0 (k 0..31)
  const int col1 = (64 + quad * 16) ^ swz;   // kk=1 (k 32..63)
  const char* const aBase = smem + wr * 16384;                 // As_half(wr)
  const char* const bBase = smem + 32768 + (wc >> 1) * 16384;  // Bs_half(wc>>1)
  const int brow = (wc & 1) << 6;  // 0/64 row offset inside B half

  f32x4 zero = {0.f, 0.f, 0.f, 0.f};
  f32x4 acc[8][4];
#pragma unroll
  for (int i = 0; i < 8; ++i)
#pragma unroll
    for (int j = 0; j < 4; ++j) acc[i][j] = zero;

  // ---- prologue: tile0 -> buf0, tile1 -> buf1; wait tile0, keep tile1 in flight
#pragma unroll
  for (int b = 0; b < 2; ++b)
#pragma unroll
    for (int op = 0; op < 2; ++op)
#pragma unroll
      for (int h = 0; h < 2; ++h)
#pragma unroll
        for (int j = 0; j < 2; ++j) stage(b, op, h, j, b);
  asm volatile("s_waitcnt vmcnt(8)" ::: "memory");
  __builtin_amdgcn_s_barrier();

  // ---- one K-tile = 4 phases. Stage placement is race-safe by construction:
  // As(buf) fully read by end of p2 -> staged at p3/p4; Bs fully read by end of
  // p3 -> staged at p4. vmcnt(8) once per tile keeps 8 loads (next tile) in flight.
  auto group = [&](const int buf, const int tt) {
    const char* As = aBase + buf * 65536;
    const char* Bs = bBase + buf * 65536;
    const bool st = (tt + 2) < NT;
    bf16x8 afl[4][2], afh[4][2], bfl[2][2], bfh[2][2];
    // ---------- phase 1: read A rows 0-63 + B rows 0-31 ; MFMA lo x lo
#pragma unroll
    for (int i = 0; i < 4; ++i) {
      afl[i][0] = *(const bf16x8*)(As + (i * 16 + l15) * 128 + col0);
      afl[i][1] = *(const bf16x8*)(As + (i * 16 + l15) * 128 + col1);
    }
#pragma unroll
    for (int j = 0; j < 2; ++j) {
      bfl[j][0] = *(const bf16x8*)(Bs + (brow + j * 16 + l15) * 128 + col0);
      bfl[j][1] = *(const bf16x8*)(Bs + (brow + j * 16 + l15) * 128 + col1);
    }
    __builtin_amdgcn_s_barrier();
    asm volatile("s_waitcnt lgkmcnt(0)" ::: "memory");
    __builtin_amdgcn_s_setprio(1);
#pragma unroll
    for (int kk = 0; kk < 2; ++kk)
#pragma unroll
      for (int i = 0; i < 4; ++i)
#pragma unroll
        for (int j = 0; j < 2; ++j)
          acc[i][j] = __builtin_amdgcn_mfma_f32_16x16x32_bf16(afl[i][kk], bfl[j][kk],
                                                              acc[i][j], 0, 0, 0);
    __builtin_amdgcn_s_setprio(0);
    __builtin_amdgcn_s_barrier();
    // ---------- phase 2: read A rows 64-127 ; MFMA hi x lo
#pragma unroll
    for (int i = 0; i < 4; ++i) {
      afh[i][0] = *(const bf16x8*)(As + ((i + 4) * 16 + l15) * 128 + col0);
      afh[i][1] = *(const bf16x8*)(As + ((i + 4) * 16 + l15) * 128 + col1);
    }
    __builtin_amdgcn_s_barrier();
    asm volatile("s_waitcnt lgkmcnt(0)" ::: "memory");
    __builtin_amdgcn_s_setprio(1);
#pragma unroll
    for (int kk = 0; kk < 2; ++kk)
#pragma unroll
      for (int i = 0; i < 4; ++i)
#pragma unroll
        for (int j = 0; j < 2; ++j)
          acc[i + 4][j] = __builtin_amdgcn_mfma_f32_16x16x32_bf16(afh[i][kk], bfl[j][kk],
                                                                  acc[i + 4][j], 0, 0, 0);
    __builtin_amdgcn_s_setprio(0);
    __builtin_amdgcn_s_barrier();
    // ---------- phase 3: read B rows 32-63 ; stage A-half0(t+2) ; MFMA hi x hi
#pragma unroll
    for (int j = 0; j < 2; ++j) {
      bfh[j][0] = *(const bf16x8*)(Bs + (brow + (j + 2) * 16 + l15) * 128 + col0);
      bfh[j][1] = *(const bf16x8*)(Bs + (brow + (j + 2) * 16 + l15) * 128 + col1);
    }
    if (st) { stage(buf, 0, 0, 0, tt + 2); stage(buf, 0, 0, 1, tt + 2); }
    __builtin_amdgcn_s_barrier();
    asm volatile("s_waitcnt lgkmcnt(0)" ::: "memory");
    __builtin_amdgcn_s_setprio(1);
#pragma unroll
    for (int kk = 0; kk < 2; ++kk)
#pragma unroll
      for (int i = 0; i < 4; ++i)
#pragma unroll
        for (int j = 0; j < 2; ++j)
          acc[i + 4][j + 2] = __builtin_amdgcn_mfma_f32_16x16x32_bf16(afh[i][kk], bfh[j][kk],
                                                                      acc[i + 4][j + 2], 0, 0, 0);
    __builtin_amdgcn_s_setprio(0);
    __builtin_amdgcn_s_barrier();
    // ---------- phase 4: stage A-half1 + B(t+2) ; counted vmcnt ; MFMA lo x hi
    if (st) {
      stage(buf, 0, 1, 0, tt + 2); stage(buf, 0, 1, 1, tt + 2);
      stage(buf, 1, 0, 0, tt + 2); stage(buf, 1, 0, 1, tt + 2);
      stage(buf, 1, 1, 0, tt + 2); stage(buf, 1, 1, 1, tt + 2);
      asm volatile("s_waitcnt vmcnt(8)" ::: "memory");  // tile t+1 landed; t+2 in flight
    } else {
      asm volatile("s_waitcnt vmcnt(0)" ::: "memory");  // tail: drain
    }
    __builtin_amdgcn_s_barrier();
    __builtin_amdgcn_s_setprio(1);
#pragma unroll
    for (int kk = 0; kk < 2; ++kk)
#pragma unroll
      for (int i = 0; i < 4; ++i)
#pragma unroll
        for (int j = 0; j < 2; ++j)
          acc[i][j + 2] = __builtin_amdgcn_mfma_f32_16x16x32_bf16(afl[i][kk], bfh[j][kk],
                                                                  acc[i][j + 2], 0, 0, 0);
    __builtin_amdgcn_s_setprio(0);
    __builtin_amdgcn_s_barrier();
  };

  for (int tt = 0; tt < NT; tt += 2) {
    group(0, tt);
    group(1, tt + 1);
  }

  // ---- epilogue ------------------------------------------------------------
  const int by = blockIdx.y;
  const int srow0 = (int)(m0 & 2047);
  const int bb = (int)(m0 >> 11);

  if (by >= 10) {  // V: transpose write [d][s], true (unpermuted) d
    const int kvh = (by - 10) * 2 + (wc >> 1);
    __bf16* Vb = Vt + ((long)(bb * NKV + kvh)) * HD * S_LEN;
#pragma unroll
    for (int i = 0; i < 8; ++i)
#pragma unroll
      for (int j = 0; j < 4; ++j) {
        const int d = brow + j * 16 + l15;
        const int s0 = srow0 + wr * 128 + i * 16 + quad * 4;
        bf16x4 o;
#pragma unroll
        for (int r = 0; r < 4; ++r) o[r] = (__bf16)acc[i][j][r];
        *(bf16x4*)(Vb + (long)d * S_LEN + s0) = o;
      }
  } else {  // Q / K: RMSNorm (combine wave-pair halves via LDS) + RoPE + gain
    float* sums = (float*)smem;
#pragma unroll
    for (int i = 0; i < 8; ++i)
#pragma unroll
      for (int r = 0; r < 4; ++r) {
        float t2 = acc[i][0][r] * acc[i][0][r] + acc[i][1][r] * acc[i][1][r] +
                   acc[i][2][r] * acc[i][2][r] + acc[i][3][r] * acc[i][3][r];
#pragma unroll
        for (int off = 1; off < 16; off <<= 1) t2 += __shfl_xor(t2, off, 64);
        if (l15 == 0) sums[(wr * 128 + i * 16 + quad * 4 + r) * 4 + wc] = t2;
      }
    __syncthreads();

    float g;
    __bf16* base;
    if (by < 8) {
      const int h = by * 2 + (wc >> 1);
      g = gain[h] * 0.08838834764831845f;  // gain * 1/sqrt(HD)
      base = Qo + ((long)(bb * NH + h)) * S_LEN * HD;
    } else {
      const int h = (by - 8) * 2 + (wc >> 1);
      g = 1.f;
      base = Ko + ((long)(bb * NKV + h)) * S_LEN * HD;
    }
#pragma unroll
    for (int i = 0; i < 8; ++i)
#pragma unroll
      for (int r = 0; r < 4; ++r) {
        const int lrow = wr * 128 + i * 16 + quad * 4 + r;
        const int srow = srow0 + lrow;
        const float rs = rsqrtf((sums[lrow * 4 + (wc & 2)] + sums[lrow * 4 + (wc & 2) + 1]) *
                                    (1.f / 128.f) +
                                1.1920928955078125e-07f);
#pragma unroll
        for (int a = 0; a < 2; ++a) {
          const int dlow = ((wc & 1) << 5) + a * 16 + l15;
          const float cv = cosT[srow * 64 + dlow];
          const float sv = sinT[srow * 64 + dlow];
          const float x1 = acc[i][2 * a][r] * rs;
          const float x2 = acc[i][2 * a + 1][r] * rs;
          base[(long)srow * HD + brow + (2 * a) * 16 + l15] = (__bf16)((x1 * cv + x2 * sv) * g);
          base[(long)srow * HD + brow + (2 * a + 1) * 16 + l15] = (__bf16)((-x1 * sv + x2 * cv) * g);
        }
      }
  }
}

// ---- attention: S^T trick, 4 waves x 16 q-rows, TK=64, high occupancy ----
// grid (32,16,2)=1024 blocks; LDS exactly 40960 B -> 4 blocks/CU (160 KB);
// __launch_bounds__(256,4) caps VGPR at 128 -> 16 waves/CU, 4/SIMD.
__global__ __launch_bounds__(256, 4) void attn_kernel(
    const __bf16* __restrict__ Q,   // [B][NH][S][HD] (perm d, pre-scaled)
    const __bf16* __restrict__ K,   // [B][NKV][S][HD] (perm d)
    const __bf16* __restrict__ Vt,  // [B][NKV][HD][S] (true d)
    const float* __restrict__ gain,
    __bf16* __restrict__ Y) {       // [B][S][NH*HD]
  __shared__ __bf16 Ks[64 * 128];   // [key][d], 16B-chunk phys = logical ^ (key&15)
  __shared__ __bf16 Vs[128 * 64];   // [d][key], 16B-chunk phys = logical ^ (d&7)
  __shared__ __bf16 Ps[4][16 * 64]; // per-wave P [q][key], 8B-chunk phys = cb ^ q

  const int t = threadIdx.x;
  const int wid = t >> 6, lane = t & 63;
  const int quad = lane >> 4, l15 = lane & 15;
  const int qt_blk = 31 - blockIdx.x;  // heavy blocks first
  const int h = blockIdx.y, b = blockIdx.z;
  const int kv = h >> 2;
  const int t0 = qt_blk * 64;
  const int r0 = t0 + wid * 16;

  const __bf16* Qb = Q + ((long)(b * NH + h)) * S_LEN * HD;
  const __bf16* Kb = K + ((long)(b * NKV + kv)) * S_LEN * HD;
  const __bf16* Vb = Vt + ((long)(b * NKV + kv)) * HD * S_LEN;
  const float M = 11.3137085f * fabsf(gain[h]);  // score bound

  // Q B-fragments: qf[c] = Q[r0+l15][c*32+quad*8+j]
  bf16x8 qf[4];
#pragma unroll
  for (int c = 0; c < 4; ++c)
    qf[c] = *(const bf16x8*)(Qb + (long)(r0 + l15) * HD + c * 32 + quad * 8);

  f32x4 zero = {0.f, 0.f, 0.f, 0.f};
  f32x4 acc[8];
#pragma unroll
  for (int d = 0; d < 8; ++d) acc[d] = zero;
  float lac = 0.f;

  // staging: 4 K-rounds (16 rows each) + 4 V-rounds (32 d-rows each), 4KB/round
  int ksrc[4], vsrc[4];
#pragma unroll
  for (int j = 0; j < 4; ++j) {
    int kr = j * 16 + (t >> 4);       // key-row 0..63
    ksrc[j] = kr * HD + (((t & 15) ^ (kr & 15)) << 3);
    int vd = j * 32 + (t >> 3);       // d-row 0..127
    vsrc[j] = vd * S_LEN + (((t & 7) ^ (vd & 7)) << 3);
  }

  const int kstart = (t0 >= WIN) ? (t0 - WIN) : 0;
  const int ntiles = (t0 + 64 - kstart) >> 6;

  for (int it = 0; it < ntiles; ++it) {
    const int kt = kstart + it * 64;
#pragma unroll
    for (int j = 0; j < 4; ++j) {
      async_load16(Kb + (long)kt * HD + ksrc[j], (char*)Ks + j * 4096 + t * 16);
      async_load16(Vb + kt + vsrc[j], (char*)Vs + j * 4096 + t * 16);
    }
    __syncthreads();  // drain staging

    if (kt <= r0 + 15 && kt + 63 >= r0 - (WIN - 1)) {
      // S^T = K·Q^T: lane q = l15, keys = kti*16 + quad*4 + r (consecutive)
#pragma unroll
      for (int kti = 0; kti < 4; ++kti) {
        bf16x8 kf[4];
#pragma unroll
        for (int c = 0; c < 4; ++c)
          kf[c] = *(const bf16x8*)(Ks + (kti * 16 + l15) * 128 +
                                   ((((c << 2) + quad) ^ l15) << 3));
        f32x4 sc = zero;
#pragma unroll
        for (int c = 0; c < 4; ++c)
          sc = __builtin_amdgcn_mfma_f32_16x16x32_bf16(kf[c], qf[c], sc, 0, 0, 0);
        const int qg = r0 + l15;
        const int kbase = kt + kti * 16 + quad * 4;
        bf16x4 pv;
#pragma unroll
        for (int r = 0; r < 4; ++r) {
          int key = kbase + r;
          float p = (key <= qg && key >= qg - (WIN - 1)) ? __expf(sc[r] - M) : 0.f;
          lac += p;
          pv[r] = (__bf16)p;
        }
        const int cb = kti * 4 + quad;  // 8B-chunk index 0..15
        *(bf16x4*)(&Ps[wid][l15 * 64 + ((cb ^ l15) << 2)]) = pv;
      }
      // P A-fragments + PV
      bf16x8 pf[2];
#pragma unroll
      for (int kc = 0; kc < 2; ++kc) {
        U8 u;
        u.h[0] = *(const bf16x4*)(&Ps[wid][l15 * 64 + (((kc * 8 + quad * 2) ^ l15) << 2)]);
        u.h[1] = *(const bf16x4*)(&Ps[wid][l15 * 64 + (((kc * 8 + quad * 2 + 1) ^ l15) << 2)]);
        pf[kc] = u.v;
      }
#pragma unroll
      for (int dt = 0; dt < 8; ++dt)
#pragma unroll
        for (int kc = 0; kc < 2; ++kc) {
          bf16x8 vf = *(const bf16x8*)(Vs + (dt * 16 + l15) * 64 +
                                       ((((kc << 2) + quad) ^ (l15 & 7)) << 3));
          acc[dt] = __builtin_amdgcn_mfma_f32_16x16x32_bf16(pf[kc], vf, acc[dt], 0, 0, 0);
        }
    }
    __syncthreads();  // protect single buffer before next staging
  }

  // epilogue: reduce l across quads (same l15 = same q), broadcast via shfl
  float s = lac;
  s += __shfl_xor(s, 16, 64);
  s += __shfl_xor(s, 32, 64);  // now every lane has l(q = its l15)
  __bf16* Yb = Y + ((long)b * S_LEN) * DIM + h * HD;
#pragma unroll
  for (int r = 0; r < 4; ++r) {
    const int row = quad * 4 + r;
    float il = 1.f / __shfl(s, row, 64);  // lane 'row' has l15==row
#pragma unroll
    for (int dt = 0; dt < 8; ++dt)
      Yb[(long)(r0 + row) * DIM + dt * 16 + l15] = (__bf16)(acc[dt][r] * il);
  }
}

// ---------------- launch ----------------
extern "C" void kernel_launch(void* const* d_in, const int* in_sizes, int n_in,
                              void* d_out, int out_size, void* d_ws, size_t ws_size,
                              hipStream_t stream) {
  (void)in_sizes; (void)n_in; (void)out_size; (void)ws_size;
  const float* x  = (const float*)d_in[0];
  const float* Wq = (const float*)d_in[1];
  const float* Wk = (const float*)d_in[2];
  const float* Wv = (const float*)d_in[3];
  const float* Wo = (const float*)d_in[4];
  const float* qg = (const float*)d_in[5];
  float* out = (float*)d_out;

  char* ws = (char*)d_ws;
  size_t off = 0;
  auto alloc = [&](size_t bytes) -> void* {
    void* p = ws + off;
    off += (bytes + 255) & ~(size_t)255;
    return p;
  };
  __bf16* xb   = (__bf16*)alloc(8388608ull * 2);      // x bf16; reused as yb
  __bf16* wqkv = (__bf16*)alloc(3072ull * 2048 * 2);  // permuted q/k weight rows
  __bf16* wob  = (__bf16*)alloc(2048ull * 2048 * 2);
  __bf16* qo   = (__bf16*)alloc((size_t)BATCH * NH * S_LEN * HD * 2);
  __bf16* ko   = (__bf16*)alloc((size_t)BATCH * NKV * S_LEN * HD * 2);
  __bf16* vt   = (__bf16*)alloc((size_t)BATCH * NKV * HD * S_LEN * 2);
  float*  cosT = (float*)alloc(2048ull * 64 * 4);
  float*  sinT = (float*)alloc(2048ull * 64 * 4);
  __bf16* yb   = xb;

  (void)hipFuncSetAttribute((const void*)gemm_qkv,
                            hipFuncAttributeMaxDynamicSharedMemorySize, 131072);

  preprocess_kernel<<<18944, 256, 0, stream>>>(x, Wq, Wk, Wv, Wo, xb, wqkv, wob,
                                               cosT, sinT);
  gemm_qkv<<<dim3(16, 12), 512, 131072, stream>>>(xb, wqkv, qg, cosT, sinT, qo, ko, vt);
  attn_kernel<<<dim3(32, 16, 2), 256, 0, stream>>>(qo, ko, vt, qg, yb);
  gemm_bt<<<dim3(32, 16), 256, 0, stream>>>(yb, wob, out, 4096, 2048, 2048);
}

// Round 3
// 260.504 us; speedup vs baseline: 1.0518x; 1.0518x over previous
//
#include <hip/hip_runtime.h>

#define S_LEN 2048
#define DIM   2048
#define NH    16
#define NKV   4
#define HD    128
#define WIN   512
#define BATCH 2

typedef __bf16 bf16x8 __attribute__((ext_vector_type(8)));
typedef __bf16 bf16x4 __attribute__((ext_vector_type(4)));
typedef float  f32x4  __attribute__((ext_vector_type(4)));

union U8 { bf16x8 v; bf16x4 h[2]; };

__device__ inline void async_load16(const void* g, void* l) {
  __builtin_amdgcn_global_load_lds(
      (const __attribute__((address_space(1))) unsigned int*)g,
      (__attribute__((address_space(3))) unsigned int*)l, 16, 0, 0);
}

// ------------- merged preprocess: x cast | weight cast+perm | rope tables ----
__global__ __launch_bounds__(256) void preprocess_kernel(
    const float* __restrict__ x,
    const float* __restrict__ Wq, const float* __restrict__ Wk,
    const float* __restrict__ Wv, const float* __restrict__ Wo,
    __bf16* __restrict__ xb, __bf16* __restrict__ wqkv, __bf16* __restrict__ wob,
    float* __restrict__ cosT, float* __restrict__ sinT) {
  const int blk = blockIdx.x, tid = threadIdx.x;
  if (blk < 8192) {
    int i = blk * 256 + tid;  // x: 2097152 float4
    float4 v = ((const float4*)x)[i];
    bf16x4 o;
    o[0] = (__bf16)v.x; o[1] = (__bf16)v.y; o[2] = (__bf16)v.z; o[3] = (__bf16)v.w;
    ((bf16x4*)xb)[i] = o;
  } else if (blk < 18432) {
    int i = (blk - 8192) * 256 + tid;  // weights: 5120 rows x 512 float4
    int orow = i >> 9, c = i & 511;
    const float* src;
    __bf16* dst;
    long soff;
    if (orow < 2048) {
      int n = orow & 127;
      int sr = (orow & ~127) + ((n >> 5) << 4) + (n & 15) + (((n >> 4) & 1) << 6);
      src = Wq; soff = (long)sr * 512 + c; dst = wqkv + (long)orow * 2048;
    } else if (orow < 2560) {
      int lr = orow - 2048, n = lr & 127;
      int sr = (lr & ~127) + ((n >> 5) << 4) + (n & 15) + (((n >> 4) & 1) << 6);
      src = Wk; soff = (long)sr * 512 + c; dst = wqkv + (long)orow * 2048;
    } else if (orow < 3072) {
      src = Wv; soff = (long)(orow - 2560) * 512 + c; dst = wqkv + (long)orow * 2048;
    } else {
      src = Wo; soff = (long)(orow - 3072) * 512 + c; dst = wob + (long)(orow - 3072) * 2048;
    }
    float4 v = ((const float4*)src)[soff];
    bf16x4 o;
    o[0] = (__bf16)v.x; o[1] = (__bf16)v.y; o[2] = (__bf16)v.z; o[3] = (__bf16)v.w;
    ((bf16x4*)dst)[c] = o;
  } else {
    int idx = (blk - 18432) * 256 + tid;  // rope: 131072
    int s = idx >> 6, d = idx & 63;
    float f = (float)s * powf(10000.f, -(float)d * (1.f / 64.f));
    float sn, cs;
    sincosf(f, &sn, &cs);
    cosT[idx] = cs;
    sinT[idx] = sn;
  }
}

// -------- O-projection GEMM: m97 structure (2-barrier, 1 buf) -----
__global__ __launch_bounds__(256) void gemm_bt(
    const __bf16* __restrict__ A, const __bf16* __restrict__ Bt,
    float* __restrict__ C, int M, int N, int K) {
  __shared__ __bf16 As[128 * 32];
  __shared__ __bf16 Bs[128 * 32];
  const int t = threadIdx.x;
  const int wid = t >> 6, lane = t & 63;
  const int quad = lane >> 4, l15 = lane & 15;
  const long m0 = (long)blockIdx.x * 128, n0 = (long)blockIdx.y * 128;
  const int wm = (wid >> 1) * 64, wn = (wid & 1) * 64;

  const __bf16* ga = A + (m0 + (t >> 2)) * (long)K + (t & 3) * 8;
  const __bf16* gb = Bt + (n0 + (t >> 2)) * (long)K + (t & 3) * 8;
  char* lA = (char*)As + wid * 1024;
  char* lB = (char*)Bs + wid * 1024;
  const long rstride = 64L * K;

  f32x4 zero = {0.f, 0.f, 0.f, 0.f};
  f32x4 acc[4][4];
#pragma unroll
  for (int i = 0; i < 4; ++i)
#pragma unroll
    for (int j = 0; j < 4; ++j) acc[i][j] = zero;

  for (int k0 = 0; k0 < K; k0 += 32) {
    async_load16(ga + k0, lA);
    async_load16(ga + k0 + rstride, lA + 4096);
    async_load16(gb + k0, lB);
    async_load16(gb + k0 + rstride, lB + 4096);
    __syncthreads();
    bf16x8 af[4], bfr[4];
#pragma unroll
    for (int i = 0; i < 4; ++i) {
      af[i] = *(const bf16x8*)(As + (wm + i * 16 + l15) * 32 + quad * 8);
      bfr[i] = *(const bf16x8*)(Bs + (wn + i * 16 + l15) * 32 + quad * 8);
    }
#pragma unroll
    for (int i = 0; i < 4; ++i)
#pragma unroll
      for (int j = 0; j < 4; ++j)
        acc[i][j] = __builtin_amdgcn_mfma_f32_16x16x32_bf16(af[i], bfr[j], acc[i][j], 0, 0, 0);
    __syncthreads();
  }

#pragma unroll
  for (int i = 0; i < 4; ++i)
#pragma unroll
    for (int j = 0; j < 4; ++j)
#pragma unroll
      for (int r = 0; r < 4; ++r)
        C[(m0 + wm + i * 16 + quad * 4 + r) * (long)N + n0 + wn + j * 16 + l15] = acc[i][j][r];
}

// -------- QKV GEMM (m97 structure) + fused RMSNorm/RoPE/gain/V-transpose ----
__global__ __launch_bounds__(256) void gemm_qkv(
    const __bf16* __restrict__ A, const __bf16* __restrict__ Bt,
    const float* __restrict__ gain,
    const float* __restrict__ cosT, const float* __restrict__ sinT,
    __bf16* __restrict__ Qo, __bf16* __restrict__ Ko, __bf16* __restrict__ Vt) {
  __shared__ __bf16 As[128 * 32];
  __shared__ __bf16 Bs[128 * 32];
  const int K = 2048;
  const int t = threadIdx.x;
  const int wid = t >> 6, lane = t & 63;
  const int quad = lane >> 4, l15 = lane & 15;
  const long m0 = (long)blockIdx.x * 128, n0 = (long)blockIdx.y * 128;
  const int wm = (wid >> 1) * 64, wn = (wid & 1) * 64;

  const __bf16* ga = A + (m0 + (t >> 2)) * (long)K + (t & 3) * 8;
  const __bf16* gb = Bt + (n0 + (t >> 2)) * (long)K + (t & 3) * 8;
  char* lA = (char*)As + wid * 1024;
  char* lB = (char*)Bs + wid * 1024;
  const long rstride = 64L * K;

  f32x4 zero = {0.f, 0.f, 0.f, 0.f};
  f32x4 acc[4][4];
#pragma unroll
  for (int i = 0; i < 4; ++i)
#pragma unroll
    for (int j = 0; j < 4; ++j) acc[i][j] = zero;

  for (int k0 = 0; k0 < K; k0 += 32) {
    async_load16(ga + k0, lA);
    async_load16(ga + k0 + rstride, lA + 4096);
    async_load16(gb + k0, lB);
    async_load16(gb + k0 + rstride, lB + 4096);
    __syncthreads();
    bf16x8 af[4], bfr[4];
#pragma unroll
    for (int i = 0; i < 4; ++i) {
      af[i] = *(const bf16x8*)(As + (wm + i * 16 + l15) * 32 + quad * 8);
      bfr[i] = *(const bf16x8*)(Bs + (wn + i * 16 + l15) * 32 + quad * 8);
    }
#pragma unroll
    for (int i = 0; i < 4; ++i)
#pragma unroll
      for (int j = 0; j < 4; ++j)
        acc[i][j] = __builtin_amdgcn_mfma_f32_16x16x32_bf16(af[i], bfr[j], acc[i][j], 0, 0, 0);
    __syncthreads();
  }

  const int by = blockIdx.y;
  const int srow0 = (int)(m0 & 2047);
  const int bb = (int)(m0 >> 11);

  if (by >= 20) {
    const int kvh = by - 20;
    __bf16* Vb = Vt + ((long)(bb * NKV + kvh)) * HD * S_LEN;
#pragma unroll
    for (int i = 0; i < 4; ++i)
#pragma unroll
      for (int j = 0; j < 4; ++j) {
        int d = wn + j * 16 + l15;
        int s0 = srow0 + wm + i * 16 + quad * 4;
        bf16x4 o;
#pragma unroll
        for (int r = 0; r < 4; ++r) o[r] = (__bf16)acc[i][j][r];
        *(bf16x4*)(Vb + (long)d * S_LEN + s0) = o;
      }
  } else {
    float* sums = (float*)As;
#pragma unroll
    for (int i = 0; i < 4; ++i)
#pragma unroll
      for (int r = 0; r < 4; ++r) {
        float t2 = acc[i][0][r] * acc[i][0][r] + acc[i][1][r] * acc[i][1][r] +
                   acc[i][2][r] * acc[i][2][r] + acc[i][3][r] * acc[i][3][r];
#pragma unroll
        for (int off = 1; off < 16; off <<= 1) t2 += __shfl_xor(t2, off, 64);
        if (l15 == 0) sums[(wm + i * 16 + quad * 4 + r) * 2 + (wn >> 6)] = t2;
      }
    __syncthreads();

    float g;
    __bf16* base;
    if (by < 16) {
      g = gain[by] * 0.08838834764831845f;
      base = Qo + ((long)(bb * NH + by)) * S_LEN * HD;
    } else {
      g = 1.f;
      base = Ko + ((long)(bb * NKV + (by - 16))) * S_LEN * HD;
    }
#pragma unroll
    for (int i = 0; i < 4; ++i)
#pragma unroll
      for (int r = 0; r < 4; ++r) {
        int lrow = wm + i * 16 + quad * 4 + r;
        int srow = srow0 + lrow;
        float rs = rsqrtf((sums[lrow * 2] + sums[lrow * 2 + 1]) * (1.f / 128.f) +
                          1.1920928955078125e-07f);
#pragma unroll
        for (int a = 0; a < 2; ++a) {
          int dlow = (wn >> 1) + a * 16 + l15;
          float cv = cosT[srow * 64 + dlow];
          float sv = sinT[srow * 64 + dlow];
          float x1 = acc[i][2 * a][r] * rs;
          float x2 = acc[i][2 * a + 1][r] * rs;
          base[(long)srow * HD + wn + (2 * a) * 16 + l15] = (__bf16)((x1 * cv + x2 * sv) * g);
          base[(long)srow * HD + wn + (2 * a + 1) * 16 + l15] = (__bf16)((-x1 * sv + x2 * cv) * g);
        }
      }
  }
}

// ---- attention: S^T trick, 8 waves x 16 q-rows, QBLK=128, TK=64 ----
// grid (16,16,2)=512 blocks; LDS 48 KB -> 2 blocks/CU resident (96 KB);
// __launch_bounds__(512,4) caps VGPR at 128 -> 16 waves/CU, 4/SIMD.
// vs QBLK=64: same per-wave math, but K/V staging + barriers per q-row halved
// (interior: 10 tiles per 128 rows vs 2x9).
__global__ __launch_bounds__(512, 4) void attn_kernel(
    const __bf16* __restrict__ Q,   // [B][NH][S][HD] (perm d, pre-scaled)
    const __bf16* __restrict__ K,   // [B][NKV][S][HD] (perm d)
    const __bf16* __restrict__ Vt,  // [B][NKV][HD][S] (true d)
    const float* __restrict__ gain,
    __bf16* __restrict__ Y) {       // [B][S][NH*HD]
  __shared__ __bf16 Ks[64 * 128];   // [key][d], 16B-chunk phys = logical ^ (key&15)
  __shared__ __bf16 Vs[128 * 64];   // [d][key], 16B-chunk phys = logical ^ (d&7)
  __shared__ __bf16 Ps[8][16 * 64]; // per-wave P [q][key], 8B-chunk phys = cb ^ q

  const int t = threadIdx.x;
  const int wid = t >> 6, lane = t & 63;
  const int quad = lane >> 4, l15 = lane & 15;
  const int qt_blk = 15 - blockIdx.x;  // heavy blocks first
  const int h = blockIdx.y, b = blockIdx.z;
  const int kv = h >> 2;
  const int t0 = qt_blk * 128;
  const int r0 = t0 + wid * 16;

  const __bf16* Qb = Q + ((long)(b * NH + h)) * S_LEN * HD;
  const __bf16* Kb = K + ((long)(b * NKV + kv)) * S_LEN * HD;
  const __bf16* Vb = Vt + ((long)(b * NKV + kv)) * HD * S_LEN;
  const float M = 11.3137085f * fabsf(gain[h]);  // score bound

  // Q B-fragments: qf[c] = Q[r0+l15][c*32+quad*8+j]
  bf16x8 qf[4];
#pragma unroll
  for (int c = 0; c < 4; ++c)
    qf[c] = *(const bf16x8*)(Qb + (long)(r0 + l15) * HD + c * 32 + quad * 8);

  f32x4 zero = {0.f, 0.f, 0.f, 0.f};
  f32x4 acc[8];
#pragma unroll
  for (int d = 0; d < 8; ++d) acc[d] = zero;
  float lac = 0.f;

  // staging with 512 threads: 2 K-rounds (32 rows each) + 2 V-rounds
  // (64 d-rows each), 8KB/round; swizzle invariants preserved:
  // Ks phys chunk = logical ^ (row&15); Vs phys chunk = logical ^ (d&7)
  int ksrc[2], vsrc[2];
#pragma unroll
  for (int j = 0; j < 2; ++j) {
    int kr = j * 32 + (t >> 4);       // key-row 0..63
    ksrc[j] = kr * HD + (((t & 15) ^ (kr & 15)) << 3);
    int vd = j * 64 + (t >> 3);       // d-row 0..127
    vsrc[j] = vd * S_LEN + (((t & 7) ^ (vd & 7)) << 3);
  }

  const int kstart = (t0 >= WIN) ? (t0 - WIN) : 0;
  const int ntiles = (t0 + 128 - kstart) >> 6;

  for (int it = 0; it < ntiles; ++it) {
    const int kt = kstart + it * 64;
#pragma unroll
    for (int j = 0; j < 2; ++j) {
      async_load16(Kb + (long)kt * HD + ksrc[j], (char*)Ks + j * 8192 + t * 16);
      async_load16(Vb + kt + vsrc[j], (char*)Vs + j * 8192 + t * 16);
    }
    __syncthreads();  // drain staging

    if (kt <= r0 + 15 && kt + 63 >= r0 - (WIN - 1)) {
      // S^T = K·Q^T: lane q = l15, keys = kti*16 + quad*4 + r (consecutive)
#pragma unroll
      for (int kti = 0; kti < 4; ++kti) {
        bf16x8 kf[4];
#pragma unroll
        for (int c = 0; c < 4; ++c)
          kf[c] = *(const bf16x8*)(Ks + (kti * 16 + l15) * 128 +
                                   ((((c << 2) + quad) ^ l15) << 3));
        f32x4 sc = zero;
#pragma unroll
        for (int c = 0; c < 4; ++c)
          sc = __builtin_amdgcn_mfma_f32_16x16x32_bf16(kf[c], qf[c], sc, 0, 0, 0);
        const int qg = r0 + l15;
        const int kbase = kt + kti * 16 + quad * 4;
        bf16x4 pv;
#pragma unroll
        for (int r = 0; r < 4; ++r) {
          int key = kbase + r;
          float p = (key <= qg && key >= qg - (WIN - 1)) ? __expf(sc[r] - M) : 0.f;
          lac += p;
          pv[r] = (__bf16)p;
        }
        const int cb = kti * 4 + quad;  // 8B-chunk index 0..15
        *(bf16x4*)(&Ps[wid][l15 * 64 + ((cb ^ l15) << 2)]) = pv;
      }
      // P A-fragments + PV
      bf16x8 pf[2];
#pragma unroll
      for (int kc = 0; kc < 2; ++kc) {
        U8 u;
        u.h[0] = *(const bf16x4*)(&Ps[wid][l15 * 64 + (((kc * 8 + quad * 2) ^ l15) << 2)]);
        u.h[1] = *(const bf16x4*)(&Ps[wid][l15 * 64 + (((kc * 8 + quad * 2 + 1) ^ l15) << 2)]);
        pf[kc] = u.v;
      }
#pragma unroll
      for (int dt = 0; dt < 8; ++dt)
#pragma unroll
        for (int kc = 0; kc < 2; ++kc) {
          bf16x8 vf = *(const bf16x8*)(Vs + (dt * 16 + l15) * 64 +
                                       ((((kc << 2) + quad) ^ (l15 & 7)) << 3));
          acc[dt] = __builtin_amdgcn_mfma_f32_16x16x32_bf16(pf[kc], vf, acc[dt], 0, 0, 0);
        }
    }
    __syncthreads();  // protect single buffer before next staging
  }

  // epilogue: reduce l across quads (same l15 = same q), broadcast via shfl
  float s = lac;
  s += __shfl_xor(s, 16, 64);
  s += __shfl_xor(s, 32, 64);  // now every lane has l(q = its l15)
  __bf16* Yb = Y + ((long)b * S_LEN) * DIM + h * HD;
#pragma unroll
  for (int r = 0; r < 4; ++r) {
    const int row = quad * 4 + r;
    float il = 1.f / __shfl(s, row, 64);  // lane 'row' has l15==row
#pragma unroll
    for (int dt = 0; dt < 8; ++dt)
      Yb[(long)(r0 + row) * DIM + dt * 16 + l15] = (__bf16)(acc[dt][r] * il);
  }
}

// ---------------- launch ----------------
extern "C" void kernel_launch(void* const* d_in, const int* in_sizes, int n_in,
                              void* d_out, int out_size, void* d_ws, size_t ws_size,
                              hipStream_t stream) {
  (void)in_sizes; (void)n_in; (void)out_size; (void)ws_size;
  const float* x  = (const float*)d_in[0];
  const float* Wq = (const float*)d_in[1];
  const float* Wk = (const float*)d_in[2];
  const float* Wv = (const float*)d_in[3];
  const float* Wo = (const float*)d_in[4];
  const float* qg = (const float*)d_in[5];
  float* out = (float*)d_out;

  char* ws = (char*)d_ws;
  size_t off = 0;
  auto alloc = [&](size_t bytes) -> void* {
    void* p = ws + off;
    off += (bytes + 255) & ~(size_t)255;
    return p;
  };
  __bf16* xb   = (__bf16*)alloc(8388608ull * 2);      // x bf16; reused as yb
  __bf16* wqkv = (__bf16*)alloc(3072ull * 2048 * 2);  // permuted q/k weight rows
  __bf16* wob  = (__bf16*)alloc(2048ull * 2048 * 2);
  __bf16* qo   = (__bf16*)alloc((size_t)BATCH * NH * S_LEN * HD * 2);
  __bf16* ko   = (__bf16*)alloc((size_t)BATCH * NKV * S_LEN * HD * 2);
  __bf16* vt   = (__bf16*)alloc((size_t)BATCH * NKV * HD * S_LEN * 2);
  float*  cosT = (float*)alloc(2048ull * 64 * 4);
  float*  sinT = (float*)alloc(2048ull * 64 * 4);
  __bf16* yb   = xb;

  preprocess_kernel<<<18944, 256, 0, stream>>>(x, Wq, Wk, Wv, Wo, xb, wqkv, wob,
                                               cosT, sinT);
  gemm_qkv<<<dim3(32, 24), 256, 0, stream>>>(xb, wqkv, qg, cosT, sinT, qo, ko, vt);
  attn_kernel<<<dim3(16, 16, 2), 512, 0, stream>>>(qo, ko, vt, qg, yb);
  gemm_bt<<<dim3(32, 16), 256, 0, stream>>>(yb, wob, out, 4096, 2048, 2048);
}

// Round 4
// 240.520 us; speedup vs baseline: 1.1392x; 1.0831x over previous
//
#include <hip/hip_runtime.h>

#define S_LEN 2048
#define DIM   2048
#define NH    16
#define NKV   4
#define HD    128
#define WIN   512
#define BATCH 2

typedef __bf16 bf16x8 __attribute__((ext_vector_type(8)));
typedef __bf16 bf16x4 __attribute__((ext_vector_type(4)));
typedef float  f32x4  __attribute__((ext_vector_type(4)));

union U8 { bf16x8 v; bf16x4 h[2]; };

__device__ inline void async_load16(const void* g, void* l) {
  __builtin_amdgcn_global_load_lds(
      (const __attribute__((address_space(1))) unsigned int*)g,
      (__attribute__((address_space(3))) unsigned int*)l, 16, 0, 0);
}

// ------------- merged preprocess: x cast | weight cast+perm | rope tables ----
__global__ __launch_bounds__(256) void preprocess_kernel(
    const float* __restrict__ x,
    const float* __restrict__ Wq, const float* __restrict__ Wk,
    const float* __restrict__ Wv, const float* __restrict__ Wo,
    __bf16* __restrict__ xb, __bf16* __restrict__ wqkv, __bf16* __restrict__ wob,
    float* __restrict__ cosT, float* __restrict__ sinT) {
  const int blk = blockIdx.x, tid = threadIdx.x;
  if (blk < 8192) {
    int i = blk * 256 + tid;  // x: 2097152 float4
    float4 v = ((const float4*)x)[i];
    bf16x4 o;
    o[0] = (__bf16)v.x; o[1] = (__bf16)v.y; o[2] = (__bf16)v.z; o[3] = (__bf16)v.w;
    ((bf16x4*)xb)[i] = o;
  } else if (blk < 18432) {
    int i = (blk - 8192) * 256 + tid;  // weights: 5120 rows x 512 float4
    int orow = i >> 9, c = i & 511;
    const float* src;
    __bf16* dst;
    long soff;
    if (orow < 2048) {
      int n = orow & 127;
      int sr = (orow & ~127) + ((n >> 5) << 4) + (n & 15) + (((n >> 4) & 1) << 6);
      src = Wq; soff = (long)sr * 512 + c; dst = wqkv + (long)orow * 2048;
    } else if (orow < 2560) {
      int lr = orow - 2048, n = lr & 127;
      int sr = (lr & ~127) + ((n >> 5) << 4) + (n & 15) + (((n >> 4) & 1) << 6);
      src = Wk; soff = (long)sr * 512 + c; dst = wqkv + (long)orow * 2048;
    } else if (orow < 3072) {
      src = Wv; soff = (long)(orow - 2560) * 512 + c; dst = wqkv + (long)orow * 2048;
    } else {
      src = Wo; soff = (long)(orow - 3072) * 512 + c; dst = wob + (long)(orow - 3072) * 2048;
    }
    float4 v = ((const float4*)src)[soff];
    bf16x4 o;
    o[0] = (__bf16)v.x; o[1] = (__bf16)v.y; o[2] = (__bf16)v.z; o[3] = (__bf16)v.w;
    ((bf16x4*)dst)[c] = o;
  } else {
    int idx = (blk - 18432) * 256 + tid;  // rope: 131072
    int s = idx >> 6, d = idx & 63;
    float f = (float)s * powf(10000.f, -(float)d * (1.f / 64.f));
    float sn, cs;
    sincosf(f, &sn, &cs);
    cosT[idx] = cs;
    sinT[idx] = sn;
  }
}

// -------- O-projection GEMM: 128x256 tile, BK=64, 8 waves (2Mx4N), 8-phase ---
// grid (32,8)=256 blocks = exactly 1/CU. T2 chunk-swizzle (inverse-swizzled
// global source, swizzled ds_read), T3/T4 counted vmcnt(6) (2-tile prefetch,
// never 0 in main loop), T5 setprio around each 16-MFMA cluster.
// Stage-race discipline (verified in the round-1 qkv port): a region is only
// re-staged after a barrier that follows every wave's lgkmcnt(0)-completed
// reads of it. sched_barrier(0) after each lgkmcnt(0) per rule #18.
__global__ __launch_bounds__(512, 2) void gemm_bt(
    const __bf16* __restrict__ A, const __bf16* __restrict__ Bt,
    float* __restrict__ C, int M, int N, int K) {
  extern __shared__ char smem[];  // 2 bufs x (A 16K + B 32K) = 96 KiB
  const int NT = K >> 6;          // 32 K-tiles
  const int t = threadIdx.x;
  const int wid = t >> 6, lane = t & 63;
  const int quad = lane >> 4, l15 = lane & 15;
  const int wr = wid >> 2, wc = wid & 3;  // 2M x 4N waves; wave tile 64x64
  const long m0 = (long)blockIdx.x * 128, n0 = (long)blockIdx.y * 256;

  // staging: linear LDS dest (t*16 within an 8 KiB unit = 64 rows x 128 B),
  // inverse-swizzled global source. phys chunk = lane&7 holds logical
  // chunk (lane&7)^(row&7).
  const int srw = (wid << 3) + (lane >> 3);       // row 0..63 within a unit
  const int c8 = (lane & 7) ^ ((lane >> 3) & 7);  // permuted 16B chunk
  const __bf16* ag = A + (m0 + srw) * (long)K + c8 * 8;
  const __bf16* bg = Bt + (n0 + srw) * (long)K + c8 * 8;

  auto stageA = [&](int buf, int j, int kt) {  // j=0..1 (rows j*64..)
    async_load16(ag + (long)(j << 6) * K + (long)kt * 64,
                 smem + buf * 49152 + j * 8192 + t * 16);
  };
  auto stageB = [&](int buf, int j, int kt) {  // j=0..3
    async_load16(bg + (long)(j << 6) * K + (long)kt * 64,
                 smem + buf * 49152 + 16384 + j * 8192 + t * 16);
  };

  // swizzled fragment read offsets: row byte = row*128, chunk byte ^= (row&7)<<4
  const int swz = (l15 & 7) << 4;
  const int col0 = (quad * 16) ^ swz;       // kk=0 (k 0..31)
  const int col1 = (64 + quad * 16) ^ swz;  // kk=1 (k 32..63)

  f32x4 zero = {0.f, 0.f, 0.f, 0.f};
  f32x4 acc[4][4];
#pragma unroll
  for (int i = 0; i < 4; ++i)
#pragma unroll
    for (int j = 0; j < 4; ++j) acc[i][j] = zero;

  // prologue: A(0),B(0),A(1)  (8 loads; B(1) staged at top of tile 0)
#pragma unroll
  for (int j = 0; j < 2; ++j) stageA(0, j, 0);
#pragma unroll
  for (int j = 0; j < 4; ++j) stageB(0, j, 0);
#pragma unroll
  for (int j = 0; j < 2; ++j) stageA(1, j, 1);

  auto tile = [&](const int buf, const int tt) {
    const char* As = smem + buf * 49152;
    const char* Bs = smem + buf * 49152 + 16384;
    // ---- top: stage B(t+1) -> buf^1 (its B-region fully consumed in tile
    // t-1's P2, protected by that tile's closing barrier); counted vmcnt
    if (tt + 1 < NT) {
#pragma unroll
      for (int j = 0; j < 4; ++j) stageB(buf ^ 1, j, tt + 1);
      asm volatile("s_waitcnt vmcnt(6)" ::: "memory");  // stage(t) landed
    } else {
      asm volatile("s_waitcnt vmcnt(0)" ::: "memory");  // tail drain
    }
    __builtin_amdgcn_s_barrier();  // all threads' stage(t) verified
    // ---- P1: read A(all) + B lo-half ; MFMA C[:, lo]
    bf16x8 af[4][2], bf[2][2];
#pragma unroll
    for (int i = 0; i < 4; ++i) {
      const int rb = (wr * 64 + i * 16 + l15) * 128;
      af[i][0] = *(const bf16x8*)(As + rb + col0);
      af[i][1] = *(const bf16x8*)(As + rb + col1);
    }
#pragma unroll
    for (int j = 0; j < 2; ++j) {
      const int rb = (wc * 64 + j * 16 + l15) * 128;
      bf[j][0] = *(const bf16x8*)(Bs + rb + col0);
      bf[j][1] = *(const bf16x8*)(Bs + rb + col1);
    }
    asm volatile("s_waitcnt lgkmcnt(0)" ::: "memory");
    __builtin_amdgcn_sched_barrier(0);
    __builtin_amdgcn_s_setprio(1);
#pragma unroll
    for (int kk = 0; kk < 2; ++kk)
#pragma unroll
      for (int i = 0; i < 4; ++i)
#pragma unroll
        for (int j = 0; j < 2; ++j)
          acc[i][j] = __builtin_amdgcn_mfma_f32_16x16x32_bf16(af[i][kk], bf[j][kk],
                                                              acc[i][j], 0, 0, 0);
    __builtin_amdgcn_s_setprio(0);
    __builtin_amdgcn_s_barrier();  // all waves' A reads complete -> A re-stageable
    // ---- P2: read B hi-half ; stage A(t+2) -> buf ; MFMA C[:, hi]
#pragma unroll
    for (int j = 0; j < 2; ++j) {
      const int rb = (wc * 64 + (j + 2) * 16 + l15) * 128;
      bf[j][0] = *(const bf16x8*)(Bs + rb + col0);
      bf[j][1] = *(const bf16x8*)(Bs + rb + col1);
    }
    if (tt + 2 < NT) {
#pragma unroll
      for (int j = 0; j < 2; ++j) stageA(buf, j, tt + 2);
    }
    asm volatile("s_waitcnt lgkmcnt(0)" ::: "memory");
    __builtin_amdgcn_sched_barrier(0);
    __builtin_amdgcn_s_setprio(1);
#pragma unroll
    for (int kk = 0; kk < 2; ++kk)
#pragma unroll
      for (int i = 0; i < 4; ++i)
#pragma unroll
        for (int j = 0; j < 2; ++j)
          acc[i][j + 2] = __builtin_amdgcn_mfma_f32_16x16x32_bf16(af[i][kk], bf[j][kk],
                                                                  acc[i][j + 2], 0, 0, 0);
    __builtin_amdgcn_s_setprio(0);
    __builtin_amdgcn_s_barrier();  // all waves' B reads complete -> B re-stageable
  };

  for (int tt = 0; tt < NT; tt += 2) {
    tile(0, tt);
    tile(1, tt + 1);
  }

#pragma unroll
  for (int i = 0; i < 4; ++i)
#pragma unroll
    for (int j = 0; j < 4; ++j)
#pragma unroll
      for (int r = 0; r < 4; ++r)
        C[(m0 + wr * 64 + i * 16 + quad * 4 + r) * (long)N + n0 + wc * 64 + j * 16 + l15] =
            acc[i][j][r];
}

// -------- QKV GEMM (m97 structure) + fused RMSNorm/RoPE/gain/V-transpose ----
__global__ __launch_bounds__(256) void gemm_qkv(
    const __bf16* __restrict__ A, const __bf16* __restrict__ Bt,
    const float* __restrict__ gain,
    const float* __restrict__ cosT, const float* __restrict__ sinT,
    __bf16* __restrict__ Qo, __bf16* __restrict__ Ko, __bf16* __restrict__ Vt) {
  __shared__ __bf16 As[128 * 32];
  __shared__ __bf16 Bs[128 * 32];
  const int K = 2048;
  const int t = threadIdx.x;
  const int wid = t >> 6, lane = t & 63;
  const int quad = lane >> 4, l15 = lane & 15;
  const long m0 = (long)blockIdx.x * 128, n0 = (long)blockIdx.y * 128;
  const int wm = (wid >> 1) * 64, wn = (wid & 1) * 64;

  const __bf16* ga = A + (m0 + (t >> 2)) * (long)K + (t & 3) * 8;
  const __bf16* gb = Bt + (n0 + (t >> 2)) * (long)K + (t & 3) * 8;
  char* lA = (char*)As + wid * 1024;
  char* lB = (char*)Bs + wid * 1024;
  const long rstride = 64L * K;

  f32x4 zero = {0.f, 0.f, 0.f, 0.f};
  f32x4 acc[4][4];
#pragma unroll
  for (int i = 0; i < 4; ++i)
#pragma unroll
    for (int j = 0; j < 4; ++j) acc[i][j] = zero;

  for (int k0 = 0; k0 < K; k0 += 32) {
    async_load16(ga + k0, lA);
    async_load16(ga + k0 + rstride, lA + 4096);
    async_load16(gb + k0, lB);
    async_load16(gb + k0 + rstride, lB + 4096);
    __syncthreads();
    bf16x8 af[4], bfr[4];
#pragma unroll
    for (int i = 0; i < 4; ++i) {
      af[i] = *(const bf16x8*)(As + (wm + i * 16 + l15) * 32 + quad * 8);
      bfr[i] = *(const bf16x8*)(Bs + (wn + i * 16 + l15) * 32 + quad * 8);
    }
#pragma unroll
    for (int i = 0; i < 4; ++i)
#pragma unroll
      for (int j = 0; j < 4; ++j)
        acc[i][j] = __builtin_amdgcn_mfma_f32_16x16x32_bf16(af[i], bfr[j], acc[i][j], 0, 0, 0);
    __syncthreads();
  }

  const int by = blockIdx.y;
  const int srow0 = (int)(m0 & 2047);
  const int bb = (int)(m0 >> 11);

  if (by >= 20) {
    const int kvh = by - 20;
    __bf16* Vb = Vt + ((long)(bb * NKV + kvh)) * HD * S_LEN;
#pragma unroll
    for (int i = 0; i < 4; ++i)
#pragma unroll
      for (int j = 0; j < 4; ++j) {
        int d = wn + j * 16 + l15;
        int s0 = srow0 + wm + i * 16 + quad * 4;
        bf16x4 o;
#pragma unroll
        for (int r = 0; r < 4; ++r) o[r] = (__bf16)acc[i][j][r];
        *(bf16x4*)(Vb + (long)d * S_LEN + s0) = o;
      }
  } else {
    float* sums = (float*)As;
#pragma unroll
    for (int i = 0; i < 4; ++i)
#pragma unroll
      for (int r = 0; r < 4; ++r) {
        float t2 = acc[i][0][r] * acc[i][0][r] + acc[i][1][r] * acc[i][1][r] +
                   acc[i][2][r] * acc[i][2][r] + acc[i][3][r] * acc[i][3][r];
#pragma unroll
        for (int off = 1; off < 16; off <<= 1) t2 += __shfl_xor(t2, off, 64);
        if (l15 == 0) sums[(wm + i * 16 + quad * 4 + r) * 2 + (wn >> 6)] = t2;
      }
    __syncthreads();

    float g;
    __bf16* base;
    if (by < 16) {
      g = gain[by] * 0.08838834764831845f;
      base = Qo + ((long)(bb * NH + by)) * S_LEN * HD;
    } else {
      g = 1.f;
      base = Ko + ((long)(bb * NKV + (by - 16))) * S_LEN * HD;
    }
#pragma unroll
    for (int i = 0; i < 4; ++i)
#pragma unroll
      for (int r = 0; r < 4; ++r) {
        int lrow = wm + i * 16 + quad * 4 + r;
        int srow = srow0 + lrow;
        float rs = rsqrtf((sums[lrow * 2] + sums[lrow * 2 + 1]) * (1.f / 128.f) +
                          1.1920928955078125e-07f);
#pragma unroll
        for (int a = 0; a < 2; ++a) {
          int dlow = (wn >> 1) + a * 16 + l15;
          float cv = cosT[srow * 64 + dlow];
          float sv = sinT[srow * 64 + dlow];
          float x1 = acc[i][2 * a][r] * rs;
          float x2 = acc[i][2 * a + 1][r] * rs;
          base[(long)srow * HD + wn + (2 * a) * 16 + l15] = (__bf16)((x1 * cv + x2 * sv) * g);
          base[(long)srow * HD + wn + (2 * a + 1) * 16 + l15] = (__bf16)((-x1 * sv + x2 * cv) * g);
        }
      }
  }
}

// ---- attention: S^T trick, 8 waves x 16 q-rows, QBLK=128, TK=64 ----
// grid (16,16,2)=512 blocks; LDS 48 KB -> 2 blocks/CU resident (96 KB);
// __launch_bounds__(512,4) caps VGPR at 128 -> 16 waves/CU, 4/SIMD.
__global__ __launch_bounds__(512, 4) void attn_kernel(
    const __bf16* __restrict__ Q,   // [B][NH][S][HD] (perm d, pre-scaled)
    const __bf16* __restrict__ K,   // [B][NKV][S][HD] (perm d)
    const __bf16* __restrict__ Vt,  // [B][NKV][HD][S] (true d)
    const float* __restrict__ gain,
    __bf16* __restrict__ Y) {       // [B][S][NH*HD]
  __shared__ __bf16 Ks[64 * 128];   // [key][d], 16B-chunk phys = logical ^ (key&15)
  __shared__ __bf16 Vs[128 * 64];   // [d][key], 16B-chunk phys = logical ^ (d&7)
  __shared__ __bf16 Ps[8][16 * 64]; // per-wave P [q][key], 8B-chunk phys = cb ^ q

  const int t = threadIdx.x;
  const int wid = t >> 6, lane = t & 63;
  const int quad = lane >> 4, l15 = lane & 15;
  const int qt_blk = 15 - blockIdx.x;  // heavy blocks first
  const int h = blockIdx.y, b = blockIdx.z;
  const int kv = h >> 2;
  const int t0 = qt_blk * 128;
  const int r0 = t0 + wid * 16;

  const __bf16* Qb = Q + ((long)(b * NH + h)) * S_LEN * HD;
  const __bf16* Kb = K + ((long)(b * NKV + kv)) * S_LEN * HD;
  const __bf16* Vb = Vt + ((long)(b * NKV + kv)) * HD * S_LEN;
  const float M = 11.3137085f * fabsf(gain[h]);  // score bound

  // Q B-fragments: qf[c] = Q[r0+l15][c*32+quad*8+j]
  bf16x8 qf[4];
#pragma unroll
  for (int c = 0; c < 4; ++c)
    qf[c] = *(const bf16x8*)(Qb + (long)(r0 + l15) * HD + c * 32 + quad * 8);

  f32x4 zero = {0.f, 0.f, 0.f, 0.f};
  f32x4 acc[8];
#pragma unroll
  for (int d = 0; d < 8; ++d) acc[d] = zero;
  float lac = 0.f;

  // staging with 512 threads: 2 K-rounds (32 rows each) + 2 V-rounds
  // (64 d-rows each), 8KB/round; swizzle invariants preserved:
  // Ks phys chunk = logical ^ (row&15); Vs phys chunk = logical ^ (d&7)
  int ksrc[2], vsrc[2];
#pragma unroll
  for (int j = 0; j < 2; ++j) {
    int kr = j * 32 + (t >> 4);       // key-row 0..63
    ksrc[j] = kr * HD + (((t & 15) ^ (kr & 15)) << 3);
    int vd = j * 64 + (t >> 3);       // d-row 0..127
    vsrc[j] = vd * S_LEN + (((t & 7) ^ (vd & 7)) << 3);
  }

  const int kstart = (t0 >= WIN) ? (t0 - WIN) : 0;
  const int ntiles = (t0 + 128 - kstart) >> 6;

  for (int it = 0; it < ntiles; ++it) {
    const int kt = kstart + it * 64;
#pragma unroll
    for (int j = 0; j < 2; ++j) {
      async_load16(Kb + (long)kt * HD + ksrc[j], (char*)Ks + j * 8192 + t * 16);
      async_load16(Vb + kt + vsrc[j], (char*)Vs + j * 8192 + t * 16);
    }
    __syncthreads();  // drain staging

    if (kt <= r0 + 15 && kt + 63 >= r0 - (WIN - 1)) {
      // S^T = K·Q^T: lane q = l15, keys = kti*16 + quad*4 + r (consecutive)
#pragma unroll
      for (int kti = 0; kti < 4; ++kti) {
        bf16x8 kf[4];
#pragma unroll
        for (int c = 0; c < 4; ++c)
          kf[c] = *(const bf16x8*)(Ks + (kti * 16 + l15) * 128 +
                                   ((((c << 2) + quad) ^ l15) << 3));
        f32x4 sc = zero;
#pragma unroll
        for (int c = 0; c < 4; ++c)
          sc = __builtin_amdgcn_mfma_f32_16x16x32_bf16(kf[c], qf[c], sc, 0, 0, 0);
        const int qg = r0 + l15;
        const int kbase = kt + kti * 16 + quad * 4;
        bf16x4 pv;
#pragma unroll
        for (int r = 0; r < 4; ++r) {
          int key = kbase + r;
          float p = (key <= qg && key >= qg - (WIN - 1)) ? __expf(sc[r] - M) : 0.f;
          lac += p;
          pv[r] = (__bf16)p;
        }
        const int cb = kti * 4 + quad;  // 8B-chunk index 0..15
        *(bf16x4*)(&Ps[wid][l15 * 64 + ((cb ^ l15) << 2)]) = pv;
      }
      // P A-fragments + PV
      bf16x8 pf[2];
#pragma unroll
      for (int kc = 0; kc < 2; ++kc) {
        U8 u;
        u.h[0] = *(const bf16x4*)(&Ps[wid][l15 * 64 + (((kc * 8 + quad * 2) ^ l15) << 2)]);
        u.h[1] = *(const bf16x4*)(&Ps[wid][l15 * 64 + (((kc * 8 + quad * 2 + 1) ^ l15) << 2)]);
        pf[kc] = u.v;
      }
#pragma unroll
      for (int dt = 0; dt < 8; ++dt)
#pragma unroll
        for (int kc = 0; kc < 2; ++kc) {
          bf16x8 vf = *(const bf16x8*)(Vs + (dt * 16 + l15) * 64 +
                                       ((((kc << 2) + quad) ^ (l15 & 7)) << 3));
          acc[dt] = __builtin_amdgcn_mfma_f32_16x16x32_bf16(pf[kc], vf, acc[dt], 0, 0, 0);
        }
    }
    __syncthreads();  // protect single buffer before next staging
  }

  // epilogue: reduce l across quads (same l15 = same q), broadcast via shfl
  float s = lac;
  s += __shfl_xor(s, 16, 64);
  s += __shfl_xor(s, 32, 64);  // now every lane has l(q = its l15)
  __bf16* Yb = Y + ((long)b * S_LEN) * DIM + h * HD;
#pragma unroll
  for (int r = 0; r < 4; ++r) {
    const int row = quad * 4 + r;
    float il = 1.f / __shfl(s, row, 64);  // lane 'row' has l15==row
#pragma unroll
    for (int dt = 0; dt < 8; ++dt)
      Yb[(long)(r0 + row) * DIM + dt * 16 + l15] = (__bf16)(acc[dt][r] * il);
  }
}

// ---------------- launch ----------------
extern "C" void kernel_launch(void* const* d_in, const int* in_sizes, int n_in,
                              void* d_out, int out_size, void* d_ws, size_t ws_size,
                              hipStream_t stream) {
  (void)in_sizes; (void)n_in; (void)out_size; (void)ws_size;
  const float* x  = (const float*)d_in[0];
  const float* Wq = (const float*)d_in[1];
  const float* Wk = (const float*)d_in[2];
  const float* Wv = (const float*)d_in[3];
  const float* Wo = (const float*)d_in[4];
  const float* qg = (const float*)d_in[5];
  float* out = (float*)d_out;

  char* ws = (char*)d_ws;
  size_t off = 0;
  auto alloc = [&](size_t bytes) -> void* {
    void* p = ws + off;
    off += (bytes + 255) & ~(size_t)255;
    return p;
  };
  __bf16* xb   = (__bf16*)alloc(8388608ull * 2);      // x bf16; reused as yb
  __bf16* wqkv = (__bf16*)alloc(3072ull * 2048 * 2);  // permuted q/k weight rows
  __bf16* wob  = (__bf16*)alloc(2048ull * 2048 * 2);
  __bf16* qo   = (__bf16*)alloc((size_t)BATCH * NH * S_LEN * HD * 2);
  __bf16* ko   = (__bf16*)alloc((size_t)BATCH * NKV * S_LEN * HD * 2);
  __bf16* vt   = (__bf16*)alloc((size_t)BATCH * NKV * HD * S_LEN * 2);
  float*  cosT = (float*)alloc(2048ull * 64 * 4);
  float*  sinT = (float*)alloc(2048ull * 64 * 4);
  __bf16* yb   = xb;

  (void)hipFuncSetAttribute((const void*)gemm_bt,
                            hipFuncAttributeMaxDynamicSharedMemorySize, 98304);

  preprocess_kernel<<<18944, 256, 0, stream>>>(x, Wq, Wk, Wv, Wo, xb, wqkv, wob,
                                               cosT, sinT);
  gemm_qkv<<<dim3(32, 24), 256, 0, stream>>>(xb, wqkv, qg, cosT, sinT, qo, ko, vt);
  attn_kernel<<<dim3(16, 16, 2), 512, 0, stream>>>(qo, ko, vt, qg, yb);
  gemm_bt<<<dim3(32, 8), 512, 98304, stream>>>(yb, wob, out, 4096, 2048, 2048);
}